// Round 3
// baseline (1830.397 us; speedup 1.0000x reference)
//
#include <hip/hip_runtime.h>

// ---------------------------------------------------------------------------
// TernaryInvertedResidual on MI355X (gfx950) — R7
//
// vs R6 (null): conv2 rebuilt as 512-thread / 8-wave blocks covering 4 output
// rows, so each SIMD hosts 2 waves of the SAME block (4 waves/SIMD with 2
// blocks/CU) — giving the CU scheduler intra-SIMD mates to overlap ds_read
// latency with MFMA issue (the regime where T4 counted-vmcnt + T5 setprio
// actually pay, per m218b; R6's 1 wave/SIMD/block was m190's null regime).
//   * wave tile unchanged: 96co x 112px, acc 7x6 f32x4 — same accumulation
//     order -> bit-identical results.
//   * smA = 6 rows x 114 x 32ci (44032 B incl pad), restaged per cb.
//   * smB TRIPLE-buffered (3 x 12288): stage at tap t -> buf (t+2)%3, last
//     read tap t-1; barrier t + MFMA register-use makes overwrite safe.
//   * uneven W-staging over 8 waves (w0-3: 2 loads/tap, w4-7: 1) -> wave-
//     uniform gate branch vmcnt(4)/vmcnt(2); tap7 2/1; tap8 0.
// LDS 80896 B -> exactly 2 blocks/CU. stats/pack/conv1/conv3 unchanged.
// ---------------------------------------------------------------------------

typedef __bf16 bf16x8 __attribute__((ext_vector_type(8)));
typedef __bf16 bf16x4 __attribute__((ext_vector_type(4)));
typedef float  f32x4  __attribute__((ext_vector_type(4)));

#define EPSBN 1e-5f

// async global->LDS, 16B per lane; LDS dest = wave-uniform base + lane*16
__device__ __forceinline__ void glds16(const void* g, void* l) {
  __builtin_amdgcn_global_load_lds(
      (const __attribute__((address_space(1))) void*)g,
      (__attribute__((address_space(3))) void*)l, 16, 0, 0);
}

__device__ __forceinline__ __bf16 tern(float w, float delta) {
  float aw = fabsf(w);
  float q = (aw > delta) ? ((w > 0.0f) ? 1.0f : -1.0f) : 0.0f;
  return (__bf16)q;
}

// ---------------- ternarize stats (deterministic, no atomics) --------------
// tensor index: 0=w1 (6144), 1=w2 (331776), 2=w3 (6144)

__global__ void stats_pass1(const float* __restrict__ w1, const float* __restrict__ w2,
                            const float* __restrict__ w3, double* __restrict__ pa) {
  __shared__ double red[256];
  int b = blockIdx.x, tid = threadIdx.x;
  int tix = b >> 5, slice = b & 31;
  const float* w = (tix == 0) ? w1 : (tix == 1) ? w2 : w3;
  int len = (tix == 1) ? 331776 : 6144;
  int per = len >> 5;
  int start = slice * per, end = start + per;
  double s = 0.0;
  for (int i = start + tid; i < end; i += 256) s += (double)fabsf(w[i]);
  red[tid] = s; __syncthreads();
  for (int off = 128; off > 0; off >>= 1) {
    if (tid < off) red[tid] += red[tid + off];
    __syncthreads();
  }
  if (tid == 0) pa[b] = red[0];
}

__global__ void stats_pass2(const float* __restrict__ w1, const float* __restrict__ w2,
                            const float* __restrict__ w3, const double* __restrict__ pa,
                            double* __restrict__ ps2, double* __restrict__ pc2) {
  __shared__ double red[256];
  int b = blockIdx.x, tid = threadIdx.x;
  int tix = b >> 5, slice = b & 31;
  const float* w = (tix == 0) ? w1 : (tix == 1) ? w2 : w3;
  int len = (tix == 1) ? 331776 : 6144;
  double tot = 0.0;
  for (int k = 0; k < 32; ++k) tot += pa[tix * 32 + k];
  float delta = 0.7f * (float)(tot / (double)len);
  int per = len >> 5;
  int start = slice * per, end = start + per;
  double s2 = 0.0, c2 = 0.0;
  for (int i = start + tid; i < end; i += 256) {
    float aw = fabsf(w[i]);
    if (aw > delta) { s2 += (double)aw; c2 += 1.0; }
  }
  red[tid] = s2; __syncthreads();
  for (int off = 128; off > 0; off >>= 1) {
    if (tid < off) red[tid] += red[tid + off];
    __syncthreads();
  }
  if (tid == 0) ps2[b] = red[0];
  __syncthreads();
  red[tid] = c2; __syncthreads();
  for (int off = 128; off > 0; off >>= 1) {
    if (tid < off) red[tid] += red[tid + off];
    __syncthreads();
  }
  if (tid == 0) pc2[b] = red[0];
}

__global__ void stats_pass3(const double* __restrict__ pa, const double* __restrict__ ps2,
                            const double* __restrict__ pc2, float* __restrict__ stats) {
  int tix = blockIdx.x;
  if (threadIdx.x != 0) return;
  double tot = 0.0, s2 = 0.0, c2 = 0.0;
  for (int k = 0; k < 32; ++k) {
    tot += pa[tix * 32 + k];
    s2  += ps2[tix * 32 + k];
    c2  += pc2[tix * 32 + k];
  }
  int len = (tix == 1) ? 331776 : 6144;
  stats[tix * 2]     = 0.7f * (float)(tot / (double)len);  // delta
  stats[tix * 2 + 1] = (float)(s2 / fmax(c2, 1.0));        // alpha
}

// ---------------- weight pack + BN fold ------------------------------------
// w1p: [co=192][ci=32]  64B rows, 16B-chunk swizzled by ((co>>2)&3)
// w2p: [tap*6+cb][co=192][ci=32]  64B rows, 16B-chunk swizzled by ((co>>2)&3)
// w3p: [kc=3][co=32][ci=64]  128B rows, 16B-chunk swizzled by (co&7)
__global__ void pack_kernel(
    const float* __restrict__ w1, const float* __restrict__ w2, const float* __restrict__ w3,
    const float* __restrict__ g1, const float* __restrict__ b1, const float* __restrict__ m1, const float* __restrict__ v1,
    const float* __restrict__ g2, const float* __restrict__ b2, const float* __restrict__ m2, const float* __restrict__ v2,
    const float* __restrict__ g3, const float* __restrict__ b3, const float* __restrict__ m3, const float* __restrict__ v3,
    const float* __restrict__ stats,
    __bf16* __restrict__ w1p, __bf16* __restrict__ w2p, __bf16* __restrict__ w3p,
    float* __restrict__ sc1, float* __restrict__ sh1,
    float* __restrict__ sc2, float* __restrict__ sh2,
    float* __restrict__ sc3, float* __restrict__ sh3) {
  int idx = blockIdx.x * 256 + threadIdx.x;
  if (idx < 331776) {
    float delta2 = stats[2];
    int c = idx / 6144, rem = idx - c * 6144;
    int co = rem >> 5, r5 = rem & 31;
    int cp = r5 >> 3, lo = r5 & 7;
    int tap = c / 6, cb = c - tap * 6;
    int ci = ((cp ^ ((co >> 2) & 3)) << 3) | lo;   // source-side chunk swizzle
    int cifull = cb * 32 + ci;
    w2p[idx] = tern(w2[(co * 192 + cifull) * 9 + tap], delta2);
    return;
  }
  idx -= 331776;
  if (idx < 6144) {  // w1p, swizzled
    int co = idx >> 5, c = (idx >> 3) & 3, lo = idx & 7;
    int ci = ((c ^ ((co >> 2) & 3)) << 3) | lo;
    w1p[idx] = tern(w1[co * 32 + ci], stats[0]);
    return;
  }
  idx -= 6144;
  if (idx < 6144) {  // w3p, swizzled
    int kc = idx >> 11, rem = idx & 2047;
    int co = rem >> 6, c = (rem >> 3) & 7, lo = rem & 7;
    int ci = ((c ^ (co & 7)) << 3) | lo;
    w3p[idx] = tern(w3[co * 192 + kc * 64 + ci], stats[4]);
    return;
  }
  idx -= 6144;
  if (idx < 192) {
    float rs = rsqrtf(v1[idx] + EPSBN);
    sc1[idx] = g1[idx] * rs * stats[1];
    sh1[idx] = b1[idx] - m1[idx] * g1[idx] * rs;
    return;
  }
  idx -= 192;
  if (idx < 192) {
    float rs = rsqrtf(v2[idx] + EPSBN);
    sc2[idx] = g2[idx] * rs * stats[3];
    sh2[idx] = b2[idx] - m2[idx] * g2[idx] * rs;
    return;
  }
  idx -= 192;
  if (idx < 32) {
    float rs = rsqrtf(v3[idx] + EPSBN);
    sc3[idx] = g3[idx] * rs * stats[5];
    sh3[idx] = b3[idx] - m3[idx] * g3[idx] * rs;
  }
}

// ---------------- conv1: 1x1 (K=32) + fused border zero --------------------
// grid (112 h, 16 n), 256 threads (4 waves). A=weights (M=co 192), B=acts
// (N=w 112). Wave co-range 48 (3 frags) x 112 px (7 frags).
__global__ __launch_bounds__(256)
void conv1_kernel(const float* __restrict__ x, const __bf16* __restrict__ w1p,
                  const float* __restrict__ scale1, const float* __restrict__ shift1,
                  __bf16* __restrict__ h1p) {
  __shared__ __bf16 smA[112 * 32];  // acts [w][ci] 64B rows, chunk-swizzled
  __shared__ __bf16 smB[192 * 32];  // weights [co][ci] 64B rows, swizzle baked
  int tid = threadIdx.x, lane = tid & 63, wave = tid >> 6;
  int h = blockIdx.x, n = blockIdx.y;

  for (int t = wave; t < 12; t += 4)
    glds16((const char*)w1p + t * 1024 + lane * 16, (char*)smB + t * 1024);

  const float* xrow = x + (long)n * 401408 + h * 112;   // + ci*12544 + w
  for (int i = 0; i < 14; ++i) {
    int f = i * 256 + tid;            // 0..3583
    int ci = f / 112, w = f - ci * 112;
    int col = ((ci >> 3) ^ ((w >> 2) & 3));
    smA[w * 32 + (col << 3) + (ci & 7)] = (__bf16)xrow[ci * 12544 + w];
  }
  __syncthreads();

  int mrow = lane & 15, quad = lane >> 4;
  int col16 = (quad ^ ((mrow >> 2) & 3)) * 16;
  int c0 = wave * 48;

  bf16x8 aw[3], bv[7];
#pragma unroll
  for (int ic = 0; ic < 3; ++ic)
    aw[ic] = *(const bf16x8*)((const char*)smB + (c0 + ic * 16 + mrow) * 64 + col16);
#pragma unroll
  for (int jp = 0; jp < 7; ++jp)
    bv[jp] = *(const bf16x8*)((const char*)smA + (jp * 16 + mrow) * 64 + col16);

  f32x4 acc[7][3];
#pragma unroll
  for (int jp = 0; jp < 7; ++jp)
#pragma unroll
    for (int ic = 0; ic < 3; ++ic) acc[jp][ic] = (f32x4)0.0f;

#pragma unroll
  for (int jp = 0; jp < 7; ++jp)
#pragma unroll
    for (int ic = 0; ic < 3; ++ic)
      acc[jp][ic] = __builtin_amdgcn_mfma_f32_16x16x32_bf16(aw[ic], bv[jp], acc[jp][ic], 0, 0, 0);

  // epilogue: BN + ReLU6 -> padded NHWC interior (hp=h+1, wp=w+1), 8B stores
  __bf16* obase = h1p + ((long)(n * 114 + h + 1) * 114 + 1) * 192;
#pragma unroll
  for (int ic = 0; ic < 3; ++ic) {
    int co0 = c0 + ic * 16 + quad * 4;
    float4 sc = *(const float4*)(scale1 + co0);
    float4 sh = *(const float4*)(shift1 + co0);
#pragma unroll
    for (int jp = 0; jp < 7; ++jp) {
      int w = jp * 16 + mrow;
      bf16x4 o;
      o[0] = (__bf16)fminf(fmaxf(acc[jp][ic][0] * sc.x + sh.x, 0.0f), 6.0f);
      o[1] = (__bf16)fminf(fmaxf(acc[jp][ic][1] * sc.y + sh.y, 0.0f), 6.0f);
      o[2] = (__bf16)fminf(fmaxf(acc[jp][ic][2] * sc.z + sh.z, 0.0f), 6.0f);
      o[3] = (__bf16)fminf(fmaxf(acc[jp][ic][3] * sc.w + sh.w, 0.0f), 6.0f);
      *(bf16x4*)(obase + w * 192 + co0) = o;
    }
  }

  // fused border zeroing of h1p
  float4 z = make_float4(0.f, 0.f, 0.f, 0.f);
  if (tid < 48) {
    int px = (tid < 24) ? 0 : 113;
    int c8 = (tid < 24) ? tid : tid - 24;
    *(float4*)((char*)h1p + ((long)((n * 114 + h + 1) * 114 + px) * 384) + c8 * 16) = z;
  }
  if (h == 0) {
    for (int c = tid; c < 2736; c += 256)
      *(float4*)((char*)h1p + (long)(n * 114) * 114 * 384 + c * 16) = z;
  }
  if (h == 111) {
    for (int c = tid; c < 2736; c += 256)
      *(float4*)((char*)h1p + (long)(n * 114 + 113) * 114 * 384 + c * 16) = z;
  }
}

// ---------------- conv2: 3x3 (K=1728) implicit GEMM, 8-wave pipelined ------
// grid (28 h-quads, 16 n), 512 threads (8 waves = 4 pg x 2 cg).
// A=weights (M=co 192), B=acts (N=448 px). Wave tile co 96 (6) x px 112 (7).
// smA: 6 input rows x 114 x 32ci (one cb), restaged per cb.
// smB: triple-buffered taps; tap t reads buf t%3, stages W(t+2)->buf (t+2)%3
// (last read at tap t-1; safe past barrier t). Gates: wave-class counted
// vmcnt (w0-3 stage 2 loads/tap, w4-7 stage 1).

#define STAGE_W(TAP, CB, B) do {                                              \
  _Pragma("unroll")                                                           \
  for (int it_ = 0; it_ < 2; ++it_) {                                         \
    int t_ = wave + it_ * 8;                                                  \
    if (t_ < 12)                                                              \
      glds16(w2b + (long)((TAP) * 6 + (CB)) * 12288 + t_ * 1024 + lane * 16,  \
             (char*)smB + (B) * 12288 + t_ * 1024);                           \
  }                                                                           \
} while (0)

#define STAGE_A(CB) do {                                                      \
  _Pragma("unroll")                                                           \
  for (int it_ = 0; it_ < 6; ++it_) {                                         \
    int t_ = wave + it_ * 8;                                                  \
    if (t_ < 43 && aoff[it_] >= 0)                                            \
      glds16(h1b + aoff[it_] + (CB) * 64, (char*)smA + t_ * 1024);            \
  }                                                                           \
} while (0)

__global__ __launch_bounds__(512, 4)
void conv2_kernel(const __bf16* __restrict__ h1p, const __bf16* __restrict__ w2p,
                  const float* __restrict__ scale2, const float* __restrict__ shift2,
                  __bf16* __restrict__ h2) {
  __shared__ __bf16 smA[688 * 32];      // 44032 B: 6x114 act rows (+pad)
  __shared__ __bf16 smB[3 * 192 * 32];  // 36864 B: weights, triple-buffered
  int tid = threadIdx.x, lane = tid & 63, wave = tid >> 6;
  int bh = blockIdx.x, n = blockIdx.y;
  int h0 = bh * 4;

  // A staging source offsets (bytes, + cb*64 at use); lane-chunk S = t*64+lane
  int aoff[6];
#pragma unroll
  for (int it = 0; it < 6; ++it) {
    int t = wave + it * 8;
    int S = t * 64 + lane;
    if (t < 43 && S < 2736) {          // 684 rows x 4 chunks
      int row = S >> 2, pos = S & 3;
      int chunkfetch = pos ^ ((row >> 2) & 3);   // source-side chunk swizzle
      int prow = row / 114, pcol = row - prow * 114;
      aoff[it] = ((n * 114 + h0 + prow) * 114 + pcol) * 384 + chunkfetch * 16;
    } else {
      aoff[it] = -1;
    }
  }

  int pg = wave >> 1, cg = wave & 1;   // pg 0..3 (output row), cg 0..1 (co half)
  int mrow = lane & 15, quad = lane >> 4;
  int col16 = (quad ^ ((mrow >> 2) & 3)) * 16;
  const char* h1b = (const char*)h1p;
  const char* w2b = (const char*)w2p;

  f32x4 acc[7][6];
#pragma unroll
  for (int jp = 0; jp < 7; ++jp)
#pragma unroll
    for (int ic = 0; ic < 6; ++ic) acc[jp][ic] = (f32x4)0.0f;

  // prologue: A(0) + W0->buf0 + W1->buf1 in flight before the first gate
  STAGE_A(0);
  STAGE_W(0, 0, 0);
  STAGE_W(1, 0, 1);

  for (int cb = 0; cb < 6; ++cb) {
#pragma unroll
    for (int tap = 0; tap < 9; ++tap) {
      if (tap <= 6) {
        STAGE_W(tap + 2, cb, (tap + 2) % 3);
        // consume W(tap); leave W(tap+1), W(tap+2) (+nothing else) in flight
        if (wave < 4) asm volatile("s_waitcnt vmcnt(4)" ::: "memory");
        else          asm volatile("s_waitcnt vmcnt(2)" ::: "memory");
      } else if (tap == 7) {
        if (wave < 4) asm volatile("s_waitcnt vmcnt(2)" ::: "memory");
        else          asm volatile("s_waitcnt vmcnt(1)" ::: "memory");
      } else {
        asm volatile("s_waitcnt vmcnt(0)" ::: "memory");
      }
      __builtin_amdgcn_s_barrier();
      __builtin_amdgcn_sched_barrier(0);

      const char* bbuf = (const char*)smB + (tap % 3) * 12288;
      bf16x8 aw[6];
#pragma unroll
      for (int ic = 0; ic < 6; ++ic)
        aw[ic] = *(const bf16x8*)(bbuf + (cg * 96 + ic * 16 + mrow) * 64 + col16);

      int dy = tap / 3, dx = tap - dy * 3;
      int base = (pg + dy) * 114 + dx;
      __builtin_amdgcn_s_setprio(1);
#pragma unroll
      for (int jp = 0; jp < 7; ++jp) {
        int row = base + jp * 16 + mrow;
        bf16x8 av = *(const bf16x8*)((const char*)smA + row * 64 +
                                     ((quad ^ ((row >> 2) & 3)) * 16));
#pragma unroll
        for (int ic = 0; ic < 6; ++ic)
          acc[jp][ic] = __builtin_amdgcn_mfma_f32_16x16x32_bf16(aw[ic], av, acc[jp][ic], 0, 0, 0);
      }
      __builtin_amdgcn_s_setprio(0);
    }

    // once per cb: drain LDS reads, fence all waves, prestage next cb
    if (cb < 5) {
      asm volatile("s_waitcnt lgkmcnt(0)" ::: "memory");
      __builtin_amdgcn_sched_barrier(0);
      __builtin_amdgcn_s_barrier();
      STAGE_A(cb + 1);
      STAGE_W(0, cb + 1, 0);
      STAGE_W(1, cb + 1, 1);
    }
  }

  // epilogue: BN + ReLU6 -> h2 linear NHWC [n][112][112][192] bf16, 8B stores
  int h = h0 + pg;
  __bf16* orow = h2 + (long)((n * 112 + h) * 112) * 192;
#pragma unroll
  for (int ic = 0; ic < 6; ++ic) {
    int co0 = cg * 96 + ic * 16 + quad * 4;
    float4 sc = *(const float4*)(scale2 + co0);
    float4 sh = *(const float4*)(shift2 + co0);
#pragma unroll
    for (int jp = 0; jp < 7; ++jp) {
      int w = jp * 16 + mrow;
      bf16x4 o;
      o[0] = (__bf16)fminf(fmaxf(acc[jp][ic][0] * sc.x + sh.x, 0.0f), 6.0f);
      o[1] = (__bf16)fminf(fmaxf(acc[jp][ic][1] * sc.y + sh.y, 0.0f), 6.0f);
      o[2] = (__bf16)fminf(fmaxf(acc[jp][ic][2] * sc.z + sh.z, 0.0f), 6.0f);
      o[3] = (__bf16)fminf(fmaxf(acc[jp][ic][3] * sc.w + sh.w, 0.0f), 6.0f);
      *(bf16x4*)(orow + w * 192 + co0) = o;
    }
  }
}

// ---------------- conv3: 1x1 (K=192) + residual ----------------------------
// grid (112 h, 16 n), 128 threads (2 waves). A=px(112), B=weights(32co).
// h2 is linear; bank swizzle applied on the staging SOURCE side.
__global__ __launch_bounds__(128)
void conv3_kernel(const __bf16* __restrict__ h2, const __bf16* __restrict__ w3p,
                  const float* __restrict__ scale3, const float* __restrict__ shift3,
                  const float* __restrict__ x, float* __restrict__ out) {
  __shared__ __bf16 smA[112 * 64];  // [w][ci64] 128B rows, chunk-swizzled
  __shared__ __bf16 smB[32 * 64];   // [co][ci64] 128B rows, swizzle baked
  int tid = threadIdx.x, lane = tid & 63, wv = tid >> 6;
  int h = blockIdx.x, n = blockIdx.y;
  int mrow = lane & 15, quad = lane >> 4;
  int swz7 = mrow & 7;

  const char* h2b = (const char*)h2 + (long)((n * 112 + h) * 112) * 384;
  f32x4 acc[7];
#pragma unroll
  for (int i = 0; i < 7; ++i) acc[i] = (f32x4)0.0f;

  for (int kc = 0; kc < 3; ++kc) {
    for (int t = wv; t < 18; t += 2) {
      if (t < 14) {
        int slot = t * 64 + lane;        // 0..895
        int w = slot >> 3, s = slot & 7;
        glds16(h2b + w * 384 + kc * 128 + (s ^ (w & 7)) * 16, (char*)smA + t * 1024);
      } else {
        glds16((const char*)w3p + kc * 4096 + (t - 14) * 1024 + lane * 16,
               (char*)smB + (t - 14) * 1024);
      }
    }
    __syncthreads();
    bf16x8 a[7][2], b[2];
#pragma unroll
    for (int ks = 0; ks < 2; ++ks) {
      int col = ((ks * 4 + quad) ^ swz7) * 16;
      b[ks] = *(const bf16x8*)((const char*)smB + (wv * 16 + mrow) * 128 + col);
#pragma unroll
      for (int i = 0; i < 7; ++i)
        a[i][ks] = *(const bf16x8*)((const char*)smA + (i * 16 + mrow) * 128 + col);
    }
    __syncthreads();
#pragma unroll
    for (int ks = 0; ks < 2; ++ks)
#pragma unroll
      for (int i = 0; i < 7; ++i)
        acc[i] = __builtin_amdgcn_mfma_f32_16x16x32_bf16(a[i][ks], b[ks], acc[i], 0, 0, 0);
  }

  // epilogue: BN (no act) + residual, fp32 float4 stores to NCHW
  int co = wv * 16 + mrow;
  float sc = scale3[co], sh = shift3[co];
  long obase = ((long)(n * 32 + co) * 112 + h) * 112;
  const float* xb = x + obase;
  float* ob = out + obase;
#pragma unroll
  for (int i = 0; i < 7; ++i) {
    int w0 = i * 16 + quad * 4;
    float4 xv = *(const float4*)(xb + w0);
    float4 o;
    o.x = acc[i][0] * sc + sh + xv.x;
    o.y = acc[i][1] * sc + sh + xv.y;
    o.z = acc[i][2] * sc + sh + xv.z;
    o.w = acc[i][3] * sc + sh + xv.w;
    *(float4*)(ob + w0) = o;
  }
}

// ---------------- launch ---------------------------------------------------
extern "C" void kernel_launch(void* const* d_in, const int* in_sizes, int n_in,
                              void* d_out, int out_size, void* d_ws, size_t ws_size,
                              hipStream_t stream) {
  const float* x  = (const float*)d_in[0];
  const float* w1 = (const float*)d_in[1];
  const float* g1 = (const float*)d_in[2];
  const float* b1 = (const float*)d_in[3];
  const float* m1 = (const float*)d_in[4];
  const float* v1 = (const float*)d_in[5];
  const float* w2 = (const float*)d_in[6];
  const float* g2 = (const float*)d_in[7];
  const float* b2 = (const float*)d_in[8];
  const float* m2 = (const float*)d_in[9];
  const float* v2 = (const float*)d_in[10];
  const float* w3 = (const float*)d_in[11];
  const float* g3 = (const float*)d_in[12];
  const float* b3 = (const float*)d_in[13];
  const float* m3 = (const float*)d_in[14];
  const float* v3 = (const float*)d_in[15];
  float* out = (float*)d_out;

  char* ws = (char*)d_ws;
  float*  stats = (float*)ws;                 // 6 floats
  double* pa    = (double*)(ws + 256);        // 96 doubles
  double* ps2   = (double*)(ws + 1024);
  double* pc2   = (double*)(ws + 1792);
  float* sc1 = (float*)(ws + 2560);
  float* sh1 = (float*)(ws + 3328);
  float* sc2 = (float*)(ws + 4096);
  float* sh2 = (float*)(ws + 4864);
  float* sc3 = (float*)(ws + 5632);
  float* sh3 = (float*)(ws + 5760);
  __bf16* w1p = (__bf16*)(ws + 8192);         // 12288 B
  __bf16* w3p = (__bf16*)(ws + 20480);        // 12288 B
  __bf16* w2p = (__bf16*)(ws + 32768);        // 663552 B
  __bf16* h1p = (__bf16*)(ws + (1 << 20));                 // 79847424 B (padded NHWC)
  __bf16* h2  = (__bf16*)(ws + (1 << 20) + 79847424);      // 77070336 B (linear NHWC)

  hipLaunchKernelGGL(stats_pass1, dim3(96), dim3(256), 0, stream, w1, w2, w3, pa);
  hipLaunchKernelGGL(stats_pass2, dim3(96), dim3(256), 0, stream, w1, w2, w3, pa, ps2, pc2);
  hipLaunchKernelGGL(stats_pass3, dim3(3), dim3(64), 0, stream, pa, ps2, pc2, stats);
  hipLaunchKernelGGL(pack_kernel, dim3(1346), dim3(256), 0, stream, w1, w2, w3,
                     g1, b1, m1, v1, g2, b2, m2, v2, g3, b3, m3, v3, stats,
                     w1p, w2p, w3p, sc1, sh1, sc2, sh2, sc3, sh3);
  hipLaunchKernelGGL(conv1_kernel, dim3(112, 16), dim3(256), 0, stream, x, w1p, sc1, sh1, h1p);
  hipLaunchKernelGGL(conv2_kernel, dim3(28, 16), dim3(512), 0, stream, h1p, w2p, sc2, sh2, h2);
  hipLaunchKernelGGL(conv3_kernel, dim3(112, 16), dim3(128), 0, stream, h2, w3p, sc3, sh3, x, out);
}

// Round 4
// 267.068 us; speedup vs baseline: 6.8537x; 6.8537x over previous
//
#include <hip/hip_runtime.h>

// ---------------------------------------------------------------------------
// TernaryInvertedResidual on MI355X (gfx950) — R8
//
// vs R6 (verified 145.6us conv2, 295.6us total): conv3 FUSED into conv2's
// epilogue. Each conv2 block computes all 192 channels of 2 output rows, so
// the 1x1 192->32 projection + BN + residual is block-local:
//   * P-row (112px x 192ci bf16, 43008 B) written to LDS (union over the
//     dead smA/smB region), w3p (12288 B) staged to LDS at 43008.
//   * conv3 executed with the SAME MFMA K-order (kc0ks0..kc2ks1), same bf16
//     P values, same swizzled w3p reads as the standalone conv3 kernel ->
//     bit-identical output. Two rows processed sequentially (one P buffer).
//   * eliminates: h2 write (77 MB), h2 read (77 MB), conv3 dispatch.
// conv2 main loop byte-identical to R6 (quad-buffered smB, counted vmcnt).
// R7 lesson: 168-reg acc => max 2 waves/SIMD; launch_bounds stays (256,2).
// stats/pack/conv1 unchanged.
// ---------------------------------------------------------------------------

typedef __bf16 bf16x8 __attribute__((ext_vector_type(8)));
typedef __bf16 bf16x4 __attribute__((ext_vector_type(4)));
typedef float  f32x4  __attribute__((ext_vector_type(4)));

#define EPSBN 1e-5f

// async global->LDS, 16B per lane; LDS dest = wave-uniform base + lane*16
__device__ __forceinline__ void glds16(const void* g, void* l) {
  __builtin_amdgcn_global_load_lds(
      (const __attribute__((address_space(1))) void*)g,
      (__attribute__((address_space(3))) void*)l, 16, 0, 0);
}

__device__ __forceinline__ __bf16 tern(float w, float delta) {
  float aw = fabsf(w);
  float q = (aw > delta) ? ((w > 0.0f) ? 1.0f : -1.0f) : 0.0f;
  return (__bf16)q;
}

// ---------------- ternarize stats (deterministic, no atomics) --------------
// tensor index: 0=w1 (6144), 1=w2 (331776), 2=w3 (6144)

__global__ void stats_pass1(const float* __restrict__ w1, const float* __restrict__ w2,
                            const float* __restrict__ w3, double* __restrict__ pa) {
  __shared__ double red[256];
  int b = blockIdx.x, tid = threadIdx.x;
  int tix = b >> 5, slice = b & 31;
  const float* w = (tix == 0) ? w1 : (tix == 1) ? w2 : w3;
  int len = (tix == 1) ? 331776 : 6144;
  int per = len >> 5;
  int start = slice * per, end = start + per;
  double s = 0.0;
  for (int i = start + tid; i < end; i += 256) s += (double)fabsf(w[i]);
  red[tid] = s; __syncthreads();
  for (int off = 128; off > 0; off >>= 1) {
    if (tid < off) red[tid] += red[tid + off];
    __syncthreads();
  }
  if (tid == 0) pa[b] = red[0];
}

__global__ void stats_pass2(const float* __restrict__ w1, const float* __restrict__ w2,
                            const float* __restrict__ w3, const double* __restrict__ pa,
                            double* __restrict__ ps2, double* __restrict__ pc2) {
  __shared__ double red[256];
  int b = blockIdx.x, tid = threadIdx.x;
  int tix = b >> 5, slice = b & 31;
  const float* w = (tix == 0) ? w1 : (tix == 1) ? w2 : w3;
  int len = (tix == 1) ? 331776 : 6144;
  double tot = 0.0;
  for (int k = 0; k < 32; ++k) tot += pa[tix * 32 + k];
  float delta = 0.7f * (float)(tot / (double)len);
  int per = len >> 5;
  int start = slice * per, end = start + per;
  double s2 = 0.0, c2 = 0.0;
  for (int i = start + tid; i < end; i += 256) {
    float aw = fabsf(w[i]);
    if (aw > delta) { s2 += (double)aw; c2 += 1.0; }
  }
  red[tid] = s2; __syncthreads();
  for (int off = 128; off > 0; off >>= 1) {
    if (tid < off) red[tid] += red[tid + off];
    __syncthreads();
  }
  if (tid == 0) ps2[b] = red[0];
  __syncthreads();
  red[tid] = c2; __syncthreads();
  for (int off = 128; off > 0; off >>= 1) {
    if (tid < off) red[tid] += red[tid + off];
    __syncthreads();
  }
  if (tid == 0) pc2[b] = red[0];
}

__global__ void stats_pass3(const double* __restrict__ pa, const double* __restrict__ ps2,
                            const double* __restrict__ pc2, float* __restrict__ stats) {
  int tix = blockIdx.x;
  if (threadIdx.x != 0) return;
  double tot = 0.0, s2 = 0.0, c2 = 0.0;
  for (int k = 0; k < 32; ++k) {
    tot += pa[tix * 32 + k];
    s2  += ps2[tix * 32 + k];
    c2  += pc2[tix * 32 + k];
  }
  int len = (tix == 1) ? 331776 : 6144;
  stats[tix * 2]     = 0.7f * (float)(tot / (double)len);  // delta
  stats[tix * 2 + 1] = (float)(s2 / fmax(c2, 1.0));        // alpha
}

// ---------------- weight pack + BN fold ------------------------------------
// w1p: [co=192][ci=32]  64B rows, 16B-chunk swizzled by ((co>>2)&3)
// w2p: [tap*6+cb][co=192][ci=32]  64B rows, 16B-chunk swizzled by ((co>>2)&3)
// w3p: [kc=3][co=32][ci=64]  128B rows, 16B-chunk swizzled by (co&7)
__global__ void pack_kernel(
    const float* __restrict__ w1, const float* __restrict__ w2, const float* __restrict__ w3,
    const float* __restrict__ g1, const float* __restrict__ b1, const float* __restrict__ m1, const float* __restrict__ v1,
    const float* __restrict__ g2, const float* __restrict__ b2, const float* __restrict__ m2, const float* __restrict__ v2,
    const float* __restrict__ g3, const float* __restrict__ b3, const float* __restrict__ m3, const float* __restrict__ v3,
    const float* __restrict__ stats,
    __bf16* __restrict__ w1p, __bf16* __restrict__ w2p, __bf16* __restrict__ w3p,
    float* __restrict__ sc1, float* __restrict__ sh1,
    float* __restrict__ sc2, float* __restrict__ sh2,
    float* __restrict__ sc3, float* __restrict__ sh3) {
  int idx = blockIdx.x * 256 + threadIdx.x;
  if (idx < 331776) {
    float delta2 = stats[2];
    int c = idx / 6144, rem = idx - c * 6144;
    int co = rem >> 5, r5 = rem & 31;
    int cp = r5 >> 3, lo = r5 & 7;
    int tap = c / 6, cb = c - tap * 6;
    int ci = ((cp ^ ((co >> 2) & 3)) << 3) | lo;   // source-side chunk swizzle
    int cifull = cb * 32 + ci;
    w2p[idx] = tern(w2[(co * 192 + cifull) * 9 + tap], delta2);
    return;
  }
  idx -= 331776;
  if (idx < 6144) {  // w1p, swizzled
    int co = idx >> 5, c = (idx >> 3) & 3, lo = idx & 7;
    int ci = ((c ^ ((co >> 2) & 3)) << 3) | lo;
    w1p[idx] = tern(w1[co * 32 + ci], stats[0]);
    return;
  }
  idx -= 6144;
  if (idx < 6144) {  // w3p, swizzled
    int kc = idx >> 11, rem = idx & 2047;
    int co = rem >> 6, c = (rem >> 3) & 7, lo = rem & 7;
    int ci = ((c ^ (co & 7)) << 3) | lo;
    w3p[idx] = tern(w3[co * 192 + kc * 64 + ci], stats[4]);
    return;
  }
  idx -= 6144;
  if (idx < 192) {
    float rs = rsqrtf(v1[idx] + EPSBN);
    sc1[idx] = g1[idx] * rs * stats[1];
    sh1[idx] = b1[idx] - m1[idx] * g1[idx] * rs;
    return;
  }
  idx -= 192;
  if (idx < 192) {
    float rs = rsqrtf(v2[idx] + EPSBN);
    sc2[idx] = g2[idx] * rs * stats[3];
    sh2[idx] = b2[idx] - m2[idx] * g2[idx] * rs;
    return;
  }
  idx -= 192;
  if (idx < 32) {
    float rs = rsqrtf(v3[idx] + EPSBN);
    sc3[idx] = g3[idx] * rs * stats[5];
    sh3[idx] = b3[idx] - m3[idx] * g3[idx] * rs;
  }
}

// ---------------- conv1: 1x1 (K=32) + fused border zero --------------------
// grid (112 h, 16 n), 256 threads (4 waves). A=weights (M=co 192), B=acts
// (N=w 112). Wave co-range 48 (3 frags) x 112 px (7 frags).
__global__ __launch_bounds__(256)
void conv1_kernel(const float* __restrict__ x, const __bf16* __restrict__ w1p,
                  const float* __restrict__ scale1, const float* __restrict__ shift1,
                  __bf16* __restrict__ h1p) {
  __shared__ __bf16 smA[112 * 32];  // acts [w][ci] 64B rows, chunk-swizzled
  __shared__ __bf16 smB[192 * 32];  // weights [co][ci] 64B rows, swizzle baked
  int tid = threadIdx.x, lane = tid & 63, wave = tid >> 6;
  int h = blockIdx.x, n = blockIdx.y;

  for (int t = wave; t < 12; t += 4)
    glds16((const char*)w1p + t * 1024 + lane * 16, (char*)smB + t * 1024);

  const float* xrow = x + (long)n * 401408 + h * 112;   // + ci*12544 + w
  for (int i = 0; i < 14; ++i) {
    int f = i * 256 + tid;            // 0..3583
    int ci = f / 112, w = f - ci * 112;
    int col = ((ci >> 3) ^ ((w >> 2) & 3));
    smA[w * 32 + (col << 3) + (ci & 7)] = (__bf16)xrow[ci * 12544 + w];
  }
  __syncthreads();

  int mrow = lane & 15, quad = lane >> 4;
  int col16 = (quad ^ ((mrow >> 2) & 3)) * 16;
  int c0 = wave * 48;

  bf16x8 aw[3], bv[7];
#pragma unroll
  for (int ic = 0; ic < 3; ++ic)
    aw[ic] = *(const bf16x8*)((const char*)smB + (c0 + ic * 16 + mrow) * 64 + col16);
#pragma unroll
  for (int jp = 0; jp < 7; ++jp)
    bv[jp] = *(const bf16x8*)((const char*)smA + (jp * 16 + mrow) * 64 + col16);

  f32x4 acc[7][3];
#pragma unroll
  for (int jp = 0; jp < 7; ++jp)
#pragma unroll
    for (int ic = 0; ic < 3; ++ic) acc[jp][ic] = (f32x4)0.0f;

#pragma unroll
  for (int jp = 0; jp < 7; ++jp)
#pragma unroll
    for (int ic = 0; ic < 3; ++ic)
      acc[jp][ic] = __builtin_amdgcn_mfma_f32_16x16x32_bf16(aw[ic], bv[jp], acc[jp][ic], 0, 0, 0);

  // epilogue: BN + ReLU6 -> padded NHWC interior (hp=h+1, wp=w+1), 8B stores
  __bf16* obase = h1p + ((long)(n * 114 + h + 1) * 114 + 1) * 192;
#pragma unroll
  for (int ic = 0; ic < 3; ++ic) {
    int co0 = c0 + ic * 16 + quad * 4;
    float4 sc = *(const float4*)(scale1 + co0);
    float4 sh = *(const float4*)(shift1 + co0);
#pragma unroll
    for (int jp = 0; jp < 7; ++jp) {
      int w = jp * 16 + mrow;
      bf16x4 o;
      o[0] = (__bf16)fminf(fmaxf(acc[jp][ic][0] * sc.x + sh.x, 0.0f), 6.0f);
      o[1] = (__bf16)fminf(fmaxf(acc[jp][ic][1] * sc.y + sh.y, 0.0f), 6.0f);
      o[2] = (__bf16)fminf(fmaxf(acc[jp][ic][2] * sc.z + sh.z, 0.0f), 6.0f);
      o[3] = (__bf16)fminf(fmaxf(acc[jp][ic][3] * sc.w + sh.w, 0.0f), 6.0f);
      *(bf16x4*)(obase + w * 192 + co0) = o;
    }
  }

  // fused border zeroing of h1p
  float4 z = make_float4(0.f, 0.f, 0.f, 0.f);
  if (tid < 48) {
    int px = (tid < 24) ? 0 : 113;
    int c8 = (tid < 24) ? tid : tid - 24;
    *(float4*)((char*)h1p + ((long)((n * 114 + h + 1) * 114 + px) * 384) + c8 * 16) = z;
  }
  if (h == 0) {
    for (int c = tid; c < 2736; c += 256)
      *(float4*)((char*)h1p + (long)(n * 114) * 114 * 384 + c * 16) = z;
  }
  if (h == 111) {
    for (int c = tid; c < 2736; c += 256)
      *(float4*)((char*)h1p + (long)(n * 114 + 113) * 114 * 384 + c * 16) = z;
  }
}

// ---------------- conv2+conv3 fused ----------------------------------------
// grid (56 h-pairs, 16 n), 256 threads (4 waves).
// Main loop identical to R6: quad-buffered weights, counted vmcnt gates.
// Epilogue: P-rows (BN+ReLU6 bf16) -> LDS, w3 staged to LDS, conv3's exact
// MFMA sequence (kc0ks0..kc2ks1) + BN + residual -> out (fp32 NCHW).
// LDS union (78336 B): main {smA 29184 | smB 4x12288} / epi {P 43008 | w3 12288}

#define STAGE_W(TAP, CB, B) do {                                              \
  _Pragma("unroll")                                                           \
  for (int it_ = 0; it_ < 3; ++it_) {                                         \
    int t_ = wave + it_ * 4;                                                  \
    glds16(w2b + (long)((TAP) * 6 + (CB)) * 12288 + t_ * 1024 + lane * 16,    \
           smBb + (B) * 12288 + t_ * 1024);                                   \
  }                                                                           \
} while (0)

#define STAGE_A(CB) do {                                                      \
  _Pragma("unroll")                                                           \
  for (int it_ = 0; it_ < 8; ++it_)                                           \
    if (aoff[it_] >= 0)                                                       \
      glds16(h1b + aoff[it_] + (CB) * 64, smAb + (wave + it_ * 4) * 1024);    \
} while (0)

__global__ __launch_bounds__(256, 2)
void conv2_kernel(const __bf16* __restrict__ h1p, const __bf16* __restrict__ w2p,
                  const float* __restrict__ scale2, const float* __restrict__ shift2,
                  const __bf16* __restrict__ w3p,
                  const float* __restrict__ scale3, const float* __restrict__ shift3,
                  const float* __restrict__ x, float* __restrict__ out) {
  __shared__ __align__(16) char smem[78336];
  char* smAb = smem;            // 29184 B act window (main loop)
  char* smBb = smem + 29184;    // 4 x 12288 B weights (main loop)
  char* Pb   = smem;            // 43008 B P-row (epilogue)
  char* w3l  = smem + 43008;    // 12288 B w3 (epilogue)
  int tid = threadIdx.x, lane = tid & 63, wave = tid >> 6;
  int bh = blockIdx.x, n = blockIdx.y;
  int h0 = bh * 2;

  // A staging source offsets (bytes, + cb*64 at use); slot s = t*64+lane
  int aoff[8];
#pragma unroll
  for (int it = 0; it < 8; ++it) {
    int t = wave + it * 4;
    int s = t * 64 + lane;
    if (s < 1824) {
      int q = s >> 2, c = s & 3;
      int q_log = c ^ ((q >> 2) & 3);
      int prow = q / 114, pcol = q - prow * 114;
      aoff[it] = ((n * 114 + h0 + prow) * 114 + pcol) * 384 + q_log * 16;
    } else {
      aoff[it] = -1;
    }
  }

  int pg = wave >> 1, cg = wave & 1;
  int mrow = lane & 15, quad = lane >> 4;
  int col16 = (quad ^ ((mrow >> 2) & 3)) * 16;
  const char* h1b = (const char*)h1p;
  const char* w2b = (const char*)w2p;

  f32x4 acc[7][6];
#pragma unroll
  for (int jp = 0; jp < 7; ++jp)
#pragma unroll
    for (int ic = 0; ic < 6; ++ic) acc[jp][ic] = (f32x4)0.0f;

  // prologue: A(0) + W0->buf0 + W1->buf1 in flight before the first gate
  STAGE_A(0);
  STAGE_W(0, 0, 0);
  STAGE_W(1, 0, 1);

  for (int cb = 0; cb < 6; ++cb) {
#pragma unroll
    for (int tap = 0; tap < 9; ++tap) {
      if (tap <= 6) {
        STAGE_W(tap + 2, cb, (tap + 2) & 3);
        asm volatile("s_waitcnt vmcnt(6)" ::: "memory");   // W(tap) + A done
      } else if (tap == 7) {
        asm volatile("s_waitcnt vmcnt(3)" ::: "memory");   // W(7) done
      } else {
        asm volatile("s_waitcnt vmcnt(0)" ::: "memory");   // W(8) done
      }
      __builtin_amdgcn_s_barrier();
      __builtin_amdgcn_sched_barrier(0);

      const char* bbuf = smBb + (tap & 3) * 12288;
      bf16x8 aw[6];
#pragma unroll
      for (int ic = 0; ic < 6; ++ic)
        aw[ic] = *(const bf16x8*)(bbuf + (cg * 96 + ic * 16 + mrow) * 64 + col16);

      int dy = tap / 3, dx = tap - dy * 3;
      int base = (pg + dy) * 114 + dx;
      __builtin_amdgcn_s_setprio(1);
#pragma unroll
      for (int jp = 0; jp < 7; ++jp) {
        int row = base + jp * 16 + mrow;
        bf16x8 av = *(const bf16x8*)(smAb + row * 64 +
                                     ((quad ^ ((row >> 2) & 3)) * 16));
#pragma unroll
        for (int ic = 0; ic < 6; ++ic)
          acc[jp][ic] = __builtin_amdgcn_mfma_f32_16x16x32_bf16(aw[ic], av, acc[jp][ic], 0, 0, 0);
      }
      __builtin_amdgcn_s_setprio(0);
    }

    // once per cb: drain LDS reads, fence all waves, prestage next cb
    if (cb < 5) {
      asm volatile("s_waitcnt lgkmcnt(0)" ::: "memory");
      __builtin_amdgcn_sched_barrier(0);
      __builtin_amdgcn_s_barrier();
      STAGE_A(cb + 1);
      STAGE_W(0, cb + 1, 0);
      STAGE_W(1, cb + 1, 1);
    }
  }

  // ---------------- fused conv3 epilogue ----------------------------------
  // All main-loop LDS reads are consumed; fence, then reuse LDS.
  asm volatile("s_waitcnt lgkmcnt(0)" ::: "memory");
  __builtin_amdgcn_s_barrier();
  __builtin_amdgcn_sched_barrier(0);

  // stage w3 (12288 B) into w3l
#pragma unroll
  for (int it = 0; it < 3; ++it) {
    int t = wave + it * 4;
    glds16((const char*)w3p + t * 1024 + lane * 16, w3l + t * 1024);
  }

  // per-lane conv3 BN params: co = (wave&1)*16 + mrow
  int cohalf = wave & 1;
  int co3 = cohalf * 16 + mrow;
  float sc3v = scale3[co3], sh3v = shift3[co3];
  int fbase = (wave >> 1) * 4;             // waves 0,1 -> frags 0..3; 2,3 -> 4..6

  // P-write lambda-ish: row rg written by waves with pg==rg
#pragma unroll
  for (int rg = 0; rg < 2; ++rg) {
    if (pg == rg) {
      // write this wave's half (cg) of P-row rg: px = jp*16+mrow, co0 = cg*96+ic*16+quad*4
#pragma unroll
      for (int ic = 0; ic < 6; ++ic) {
        int co0 = cg * 96 + ic * 16 + quad * 4;
        float4 sc = *(const float4*)(scale2 + co0);
        float4 sh = *(const float4*)(shift2 + co0);
        int kc = co0 >> 6, c6 = co0 & 63;
        int chunk = c6 >> 3, off = c6 & 7;
#pragma unroll
        for (int jp = 0; jp < 7; ++jp) {
          int px = jp * 16 + mrow;
          bf16x4 o;
          o[0] = (__bf16)fminf(fmaxf(acc[jp][ic][0] * sc.x + sh.x, 0.0f), 6.0f);
          o[1] = (__bf16)fminf(fmaxf(acc[jp][ic][1] * sc.y + sh.y, 0.0f), 6.0f);
          o[2] = (__bf16)fminf(fmaxf(acc[jp][ic][2] * sc.z + sh.z, 0.0f), 6.0f);
          o[3] = (__bf16)fminf(fmaxf(acc[jp][ic][3] * sc.w + sh.w, 0.0f), 6.0f);
          *(bf16x4*)(Pb + px * 384 + kc * 128 + ((chunk ^ (px & 7)) * 16) + off * 2) = o;
        }
      }
    }
    // P writes + (rg==0: w3 stage) must land before reads
    if (rg == 0)
      asm volatile("s_waitcnt vmcnt(0) lgkmcnt(0)" ::: "memory");
    else
      asm volatile("s_waitcnt lgkmcnt(0)" ::: "memory");
    __builtin_amdgcn_s_barrier();
    __builtin_amdgcn_sched_barrier(0);

    // conv3 on row rg: wave covers co 16*(wave&1).. and px frags fbase..(+3|+2)
    f32x4 acc3[4];
#pragma unroll
    for (int f = 0; f < 4; ++f) acc3[f] = (f32x4)0.0f;
    int swz = mrow & 7;
#pragma unroll
    for (int kc = 0; kc < 3; ++kc) {
      bf16x8 b0 = *(const bf16x8*)(w3l + kc * 4096 + (cohalf * 16 + mrow) * 128 +
                                   ((quad ^ swz) * 16));
      bf16x8 b1 = *(const bf16x8*)(w3l + kc * 4096 + (cohalf * 16 + mrow) * 128 +
                                   (((4 + quad) ^ swz) * 16));
#pragma unroll
      for (int f = 0; f < 4; ++f) {
        if (fbase + f < 7) {
          int pr = (fbase + f) * 16 + mrow;
          bf16x8 a0 = *(const bf16x8*)(Pb + pr * 384 + kc * 128 + ((quad ^ swz) * 16));
          bf16x8 a1 = *(const bf16x8*)(Pb + pr * 384 + kc * 128 + (((4 + quad) ^ swz) * 16));
          acc3[f] = __builtin_amdgcn_mfma_f32_16x16x32_bf16(a0, b0, acc3[f], 0, 0, 0);
          acc3[f] = __builtin_amdgcn_mfma_f32_16x16x32_bf16(a1, b1, acc3[f], 0, 0, 0);
        }
      }
    }
    // BN (no act) + residual, fp32 float4 stores to NCHW
    int h = h0 + rg;
    long obase = ((long)(n * 32 + co3) * 112 + h) * 112;
    const float* xb = x + obase;
    float* ob = out + obase;
#pragma unroll
    for (int f = 0; f < 4; ++f) {
      if (fbase + f < 7) {
        int w0 = (fbase + f) * 16 + quad * 4;
        float4 xv = *(const float4*)(xb + w0);
        float4 o;
        o.x = acc3[f][0] * sc3v + sh3v + xv.x;
        o.y = acc3[f][1] * sc3v + sh3v + xv.y;
        o.z = acc3[f][2] * sc3v + sh3v + xv.z;
        o.w = acc3[f][3] * sc3v + sh3v + xv.w;
        *(float4*)(ob + w0) = o;
      }
    }
    // before overwriting Pb with row 1 (readers' a-reads were consumed by MFMAs)
    if (rg == 0) {
      asm volatile("s_waitcnt lgkmcnt(0)" ::: "memory");
      __builtin_amdgcn_s_barrier();
      __builtin_amdgcn_sched_barrier(0);
    }
  }
}

// ---------------- launch ---------------------------------------------------
extern "C" void kernel_launch(void* const* d_in, const int* in_sizes, int n_in,
                              void* d_out, int out_size, void* d_ws, size_t ws_size,
                              hipStream_t stream) {
  const float* x  = (const float*)d_in[0];
  const float* w1 = (const float*)d_in[1];
  const float* g1 = (const float*)d_in[2];
  const float* b1 = (const float*)d_in[3];
  const float* m1 = (const float*)d_in[4];
  const float* v1 = (const float*)d_in[5];
  const float* w2 = (const float*)d_in[6];
  const float* g2 = (const float*)d_in[7];
  const float* b2 = (const float*)d_in[8];
  const float* m2 = (const float*)d_in[9];
  const float* v2 = (const float*)d_in[10];
  const float* w3 = (const float*)d_in[11];
  const float* g3 = (const float*)d_in[12];
  const float* b3 = (const float*)d_in[13];
  const float* m3 = (const float*)d_in[14];
  const float* v3 = (const float*)d_in[15];
  float* out = (float*)d_out;

  char* ws = (char*)d_ws;
  float*  stats = (float*)ws;                 // 6 floats
  double* pa    = (double*)(ws + 256);        // 96 doubles
  double* ps2   = (double*)(ws + 1024);
  double* pc2   = (double*)(ws + 1792);
  float* sc1 = (float*)(ws + 2560);
  float* sh1 = (float*)(ws + 3328);
  float* sc2 = (float*)(ws + 4096);
  float* sh2 = (float*)(ws + 4864);
  float* sc3 = (float*)(ws + 5632);
  float* sh3 = (float*)(ws + 5760);
  __bf16* w1p = (__bf16*)(ws + 8192);         // 12288 B
  __bf16* w3p = (__bf16*)(ws + 20480);        // 12288 B
  __bf16* w2p = (__bf16*)(ws + 32768);        // 663552 B
  __bf16* h1p = (__bf16*)(ws + (1 << 20));    // 79847424 B (padded NHWC)

  hipLaunchKernelGGL(stats_pass1, dim3(96), dim3(256), 0, stream, w1, w2, w3, pa);
  hipLaunchKernelGGL(stats_pass2, dim3(96), dim3(256), 0, stream, w1, w2, w3, pa, ps2, pc2);
  hipLaunchKernelGGL(stats_pass3, dim3(3), dim3(64), 0, stream, pa, ps2, pc2, stats);
  hipLaunchKernelGGL(pack_kernel, dim3(1346), dim3(256), 0, stream, w1, w2, w3,
                     g1, b1, m1, v1, g2, b2, m2, v2, g3, b3, m3, v3, stats,
                     w1p, w2p, w3p, sc1, sh1, sc2, sh2, sc3, sh3);
  hipLaunchKernelGGL(conv1_kernel, dim3(112, 16), dim3(256), 0, stream, x, w1p, sc1, sh1, h1p);
  hipLaunchKernelGGL(conv2_kernel, dim3(56, 16), dim3(256), 0, stream, h1p, w2p, sc2, sh2,
                     w3p, sc3, sh3, x, out);
}